// Round 8
// baseline (125.851 us; speedup 1.0000x reference)
//
#include <hip/hip_runtime.h>

// PostProcessor3D: threshold(>0.9) + 5x5x5 stride-1 maxpool + strict-local-max
// mask on [64,512,512] fp32. Memory-bound separable stencil.
//
// R8 = R7 with the center-ring phase fixed: output at iter t is the window
// centered at slice t-2, whose center values were stored at iter t-2 -> slot
// (t+3)%5. R7 read (t+1)%5 = slice t-4's center -> absmax 1.0.
//
// R7 design: kill the barrier vmcnt drain. HIP __syncthreads lowers to
// "s_waitcnt vmcnt(0) lgkmcnt(0); s_barrier" -- it drains the prefetch loads
// issued just before it, exposing ~900 cyc HBM latency EVERY slice (why
// R4/R5/R6 plateaued at ~2.8 TB/s). Replace with a raw barrier that only
// waits lgkmcnt(0) (LDS visibility); global loads stay in flight across it.
// Distance-2 register prefetch so ~2 iterations of compute cover the latency
// (compiler still inserts vmcnt waits before the *use* of each load's regs).
//
// Structure: 256-thread blocks, tile W=64 x H=16, DCHUNK=8, grid 2048.
// Single-buffered raw (20x19 quads) + wm (20x17 quads) = 11.5 KB LDS.
// Per slice t: [stage raw from pf(t%2); prefetch slice t+2 -> pf(t%2)]
//   B1 [W-max -> wm; cen ring] B2 [H-max -> win ring; D-max + output t-4].
// Hazards: raw reads(t) vs raw write(t+1): B2 between. wm reads(t) vs wm
// write(t+1): B1(t+1) between. Loop fully unrolled -> all ring indices are
// compile-time constants (no scratch spill; R3 lesson).
// Padding with 0 == reference -inf padding (thresholded values >= 0, center
// always in its own window).

#define THRESH 0.9f

constexpr int D = 64, H = 512, W = 512;
constexpr int TW = 64;                    // tile width in floats
constexpr int TH = 16;                    // tile height
constexpr int DCHUNK = 8;                 // depth outputs per block
constexpr int HALO = 2;
constexpr int LROWS = TH + 2 * HALO;      // 20 staged rows
constexpr int RAWQ  = TW / 4 + 2;         // 18 quads/row: [w0-4, w0+68)
constexpr int RAWQ_S = RAWQ + 1;          // 19: de-phase rows
constexpr int WMQ   = TW / 4;             // 16 quads/row
constexpr int WMQ_S = WMQ + 1;            // 17
constexpr int NS = DCHUNK + 2 * HALO;     // 12 slices staged per block

typedef float floatx4 __attribute__((ext_vector_type(4)));

__device__ __forceinline__ void barrier_no_drain() {
    // LDS writes visible (lgkmcnt), global loads stay in flight (no vmcnt).
    asm volatile("s_waitcnt lgkmcnt(0)\n\ts_barrier" ::: "memory");
}

__device__ __forceinline__ float4 thresh4(float4 v) {
    v.x = (v.x > THRESH) ? v.x : 0.f;
    v.y = (v.y > THRESH) ? v.y : 0.f;
    v.z = (v.z > THRESH) ? v.z : 0.f;
    v.w = (v.w > THRESH) ? v.w : 0.f;
    return v;
}

__device__ __forceinline__ float4 max4(float4 a, float4 b) {
    return make_float4(fmaxf(a.x, b.x), fmaxf(a.y, b.y),
                       fmaxf(a.z, b.z), fmaxf(a.w, b.w));
}

// 5-tap sliding max over 12 floats (3 quads) -> 4 outputs.
// f[i] = float at (4*c_out + i); out[j] = max(f[2+j .. 6+j]).
__device__ __forceinline__ float4 wmax5(float4 a, float4 b, float4 c) {
    const float f2 = a.z, f3 = a.w, f4 = b.x, f5 = b.y, f6 = b.z, f7 = b.w;
    const float f8 = c.x, f9 = c.y;
    const float m45 = fmaxf(f4, f5);
    const float m56 = fmaxf(f5, f6);
    const float m345 = fmaxf(f3, m45);
    const float m456 = fmaxf(f4, m56);
    const float m567 = fmaxf(m56, f7);
    const float m678 = fmaxf(fmaxf(f6, f7), f8);
    float4 r;
    r.x = fmaxf(fmaxf(f2, f6), m345);
    r.y = fmaxf(fmaxf(f3, f7), m456);
    r.z = fmaxf(fmaxf(f4, f8), m567);
    r.w = fmaxf(fmaxf(f5, f9), m678);
    return r;
}

__global__ __launch_bounds__(256)
void peak3d_kernel(const float* __restrict__ in, float* __restrict__ out) {
    __shared__ float4 raw[LROWS * RAWQ_S];    // 380 quads = 6080 B
    __shared__ float4 wm [LROWS * WMQ_S];     // 340 quads = 5440 B

    const int tx = threadIdx.x;               // 0..15 (quad column)
    const int ty = threadIdx.y;               // 0..15 (row)
    const int tid = ty * 16 + tx;

    const int w0 = blockIdx.x * TW;
    const int h0 = blockIdx.y * TH;
    const int d0 = blockIdx.z * DCHUNK;

    // Staging map: 20 rows x 18 quads = 360 quads, <=2 per thread.
    const int q0 = tid;
    const int q1 = tid + 256;
    const int r0 = q0 / RAWQ, c0 = q0 % RAWQ;
    const int r1 = q1 / RAWQ, c1 = q1 % RAWQ;
    const int lds0 = r0 * RAWQ_S + c0;
    const int lds1 = r1 * RAWQ_S + c1;
    const int gh0 = h0 + r0 - HALO, gw0 = w0 + 4 * c0 - 4;
    const int gh1 = h0 + r1 - HALO, gw1 = w0 + 4 * c1 - 4;
    const bool has1 = (q1 < LROWS * RAWQ);
    const bool ib0 = (gh0 >= 0 && gh0 < H && gw0 >= 0 && gw0 < W);
    const bool ib1 = has1 && (gh1 >= 0 && gh1 < H && gw1 >= 0 && gw1 < W);
    const size_t off0 = ib0 ? ((size_t)gh0 * W + gw0) : 0;
    const size_t off1 = ib1 ? ((size_t)gh1 * W + gw1) : 0;

    const float4 zero4 = make_float4(0.f, 0.f, 0.f, 0.f);
    float4 win[5], cen[5];
#pragma unroll
    for (int k = 0; k < 5; ++k) { win[k] = zero4; cen[k] = zero4; }

    auto loadSlice = [&](int dd, float4& a, float4& b) {
        a = zero4; b = zero4;
        if (dd >= 0 && dd < D) {
            const size_t base = (size_t)dd * (H * W);
            if (ib0) a = thresh4(*reinterpret_cast<const float4*>(in + base + off0));
            if (ib1) b = thresh4(*reinterpret_cast<const float4*>(in + base + off1));
        }
    };

    // Distance-2 prefetch: two register slots (constant-indexed after unroll).
    float4 pfa[2], pfb[2];
    loadSlice(d0 - HALO + 0, pfa[0], pfb[0]);
    loadSlice(d0 - HALO + 1, pfa[1], pfb[1]);

#pragma unroll
    for (int t = 0; t < NS; ++t) {
        const int slot = t & 1;

        // ---- stage slice t, then refill slot with slice t+2 ----
        raw[lds0] = pfa[slot];
        if (has1) raw[lds1] = pfb[slot];
        if (t + 2 < NS) loadSlice(d0 - HALO + t + 2, pfa[slot], pfb[slot]);

        barrier_no_drain();                   // B1: raw visible

        // ---- W-stage: row-wise 5-max -> wm; center ring ----
        {
            const float4* rp = &raw[ty * RAWQ_S + tx];
            wm[ty * WMQ_S + tx] = wmax5(rp[0], rp[1], rp[2]);
            if (tid < (LROWS - TH) * WMQ) {   // tail rows 16..19
                const int r = TH + (tid >> 4), c = tid & 15;
                const float4* rq = &raw[r * RAWQ_S + c];
                wm[r * WMQ_S + c] = wmax5(rq[0], rq[1], rq[2]);
            }
            cen[t % 5] = raw[(ty + HALO) * RAWQ_S + (tx + 1)];
        }

        barrier_no_drain();                   // B2: wm visible, raw reads done

        // ---- H-stage: 5-row max -> win ring; D-max + output ----
        {
            const float4* wp = &wm[ty * WMQ_S + tx];
            float4 hv = wp[0];
            hv = max4(hv, wp[1 * WMQ_S]);
            hv = max4(hv, wp[2 * WMQ_S]);
            hv = max4(hv, wp[3 * WMQ_S]);
            hv = max4(hv, wp[4 * WMQ_S]);
            win[t % 5] = hv;

            if (t >= 4) {
                const int dout = d0 + (t - 4);
                const float4 mp = max4(max4(max4(win[0], win[1]),
                                            max4(win[2], win[3])), win[4]);
                // window slices t-4..t centered at slice t-2; cen slot
                // written at iter t-2 is (t-2)%5 == (t+3)%5.
                const float4 tcc = cen[(t + 3) % 5];
                floatx4 res;
                res.x = (mp.x > 0.f && mp.x == tcc.x) ? mp.x : 0.f;
                res.y = (mp.y > 0.f && mp.y == tcc.y) ? mp.y : 0.f;
                res.z = (mp.z > 0.f && mp.z == tcc.z) ? mp.z : 0.f;
                res.w = (mp.w > 0.f && mp.w == tcc.w) ? mp.w : 0.f;
                floatx4* op = reinterpret_cast<floatx4*>(
                    out + (size_t)dout * (H * W) +
                    (size_t)(h0 + ty) * W + (w0 + 4 * tx));
                __builtin_nontemporal_store(res, op);
            }
        }
        // Next iter's raw writes: separated from this iter's raw reads by B2.
        // Next iter's wm writes: separated from this iter's wm reads by its B1.
    }
}

extern "C" void kernel_launch(void* const* d_in, const int* in_sizes, int n_in,
                              void* d_out, int out_size, void* d_ws, size_t ws_size,
                              hipStream_t stream) {
    const float* in = (const float*)d_in[0];
    float* out = (float*)d_out;
    dim3 grid(W / TW, H / TH, D / DCHUNK);    // 8 x 32 x 8 = 2048 blocks
    dim3 block(16, 16, 1);
    hipLaunchKernelGGL(peak3d_kernel, grid, block, 0, stream, in, out);
}